// Round 3
// baseline (25.905 us; speedup 1.0000x reference)
//
#include <hip/hip_runtime.h>
#include <math.h>

// OSDT: soft decision tree leaf probabilities.
// x:[B,512] f32, w:[10,512] f32, thr:[10], lt:[10]  ->  out:[B,1024] f32
// Memory-bound: ~32MiB read + ~64MiB write => roofline ~16us at 6.3 TB/s.

#define IDIM   512
#define DEPTH  10
#define NLEAF  1024
#define ROWS_PER_WAVE 4

__global__ __launch_bounds__(256, 2) void osdt_kernel(
    const float* __restrict__ x,
    const float* __restrict__ sw,
    const float* __restrict__ thr,
    const float* __restrict__ lt,
    float* __restrict__ out,
    int batch)
{
    // Stage the 20 KiB weight matrix into LDS once per block (float4 layout).
    __shared__ float4 s_w4[DEPTH * IDIM / 4];   // 1280 float4 = 20 KiB
    {
        const float4* src = reinterpret_cast<const float4*>(sw);
        #pragma unroll
        for (int i = 0; i < (DEPTH * IDIM / 4) / 256; ++i)   // 5 iters
            s_w4[threadIdx.x + i * 256] = src[threadIdx.x + i * 256];
    }
    // Thresholds / temperature scales into registers (statically indexed).
    float thrv[DEPTH], sclv[DEPTH];
    #pragma unroll
    for (int d = 0; d < DEPTH; ++d) {
        thrv[d] = thr[d];
        sclv[d] = __expf(-lt[d]);
    }
    __syncthreads();

    const int lane  = threadIdx.x & 63;
    const int wave  = threadIdx.x >> 6;
    const int gwave = blockIdx.x * 4 + wave;            // 0..4095

    // Hoist this lane's weight fragments LDS -> 80 VGPRs (loop-invariant).
    // Lane holds w[d][4*lane .. +3] and w[d][256+4*lane .. +3].
    float4 wa[DEPTH], wb[DEPTH];
    #pragma unroll
    for (int d = 0; d < DEPTH; ++d) {
        wa[d] = s_w4[d * 128 + lane];
        wb[d] = s_w4[d * 128 + 64 + lane];
    }

    const size_t base_row = (size_t)gwave * ROWS_PER_WAVE;
    if ((int)base_row >= batch) return;

    // Prefetch first row's x fragment (two coalesced float4 loads: bytes
    // 0..1023 and 1024..2047 of the row, 16B/lane contiguous).
    const float4* xr0 = reinterpret_cast<const float4*>(x + base_row * IDIM);
    float4 xa = xr0[lane];
    float4 xb = xr0[64 + lane];

    #pragma unroll 1
    for (int r = 0; r < ROWS_PER_WAVE; ++r) {
        const float4 cxa = xa, cxb = xb;
        // Prefetch next row (clamped; redundant L1-hit reload on last iter).
        {
            const int nr = (r + 1 < ROWS_PER_WAVE) ? r + 1 : r;
            const float4* xrn =
                reinterpret_cast<const float4*>(x + (base_row + nr) * IDIM);
            xa = xrn[lane];
            xb = xrn[64 + lane];
        }

        // Per-depth partial dot products (8 elements per lane).
        float part[DEPTH];
        #pragma unroll
        for (int d = 0; d < DEPTH; ++d) {
            part[d] = cxa.x * wa[d].x + cxa.y * wa[d].y +
                      cxa.z * wa[d].z + cxa.w * wa[d].w +
                      cxb.x * wb[d].x + cxb.y * wb[d].y +
                      cxb.z * wb[d].z + cxb.w * wb[d].w;
        }
        // Butterfly reduce across the 64-lane wave; result broadcast to all
        // lanes (xor butterfly leaves every lane with the full sum).
        #pragma unroll
        for (int d = 0; d < DEPTH; ++d) {
            #pragma unroll
            for (int m = 1; m < 64; m <<= 1)
                part[d] += __shfl_xor(part[d], m, 64);
        }

        // Sigmoids. Clamp |z|<=30: dot of 512 normals => |z| up to ~100 and
        // expf overflows to inf (inf*0 = NaN). sigmoid(30)=1-9e-14, far
        // inside the 2e-2 tolerance.
        float lv[DEPTH], rv[DEPTH];
        #pragma unroll
        for (int d = 0; d < DEPTH; ++d) {
            float z = (part[d] - thrv[d]) * sclv[d];
            z = fminf(fmaxf(z, -30.0f), 30.0f);
            const float e  = __expf(-z);
            const float rr = 1.0f / (1.0f + e);   // sigmoid(z)
            rv[d] = rr;
            lv[d] = e * rr;                       // sigmoid(-z)
        }

        // Leaf l = j*256 + lane*4 + k:
        //   bits 0,1 of l = k  -> depths 0,1   (head[k])
        //   bits 2..7 of l = lane bits 0..5 -> depths 2..7 (base)
        //   bits 8,9 of l = j  -> depths 8,9   (tail[j])
        float head[4], tail[4];
        head[0] = lv[0] * lv[1];  head[1] = rv[0] * lv[1];
        head[2] = lv[0] * rv[1];  head[3] = rv[0] * rv[1];
        tail[0] = lv[8] * lv[9];  tail[1] = rv[8] * lv[9];
        tail[2] = lv[8] * rv[9];  tail[3] = rv[8] * rv[9];

        float base = ((lane >> 0) & 1) ? rv[2] : lv[2];
        base *= ((lane >> 1) & 1) ? rv[3] : lv[3];
        base *= ((lane >> 2) & 1) ? rv[4] : lv[4];
        base *= ((lane >> 3) & 1) ? rv[5] : lv[5];
        base *= ((lane >> 4) & 1) ? rv[6] : lv[6];
        base *= ((lane >> 5) & 1) ? rv[7] : lv[7];

        // 4 coalesced float4 stores (lane*16B -> contiguous 1 KiB each).
        float* orow = out + (base_row + r) * NLEAF;
        #pragma unroll
        for (int j = 0; j < 4; ++j) {
            const float bt = base * tail[j];
            float4 v;
            v.x = bt * head[0];
            v.y = bt * head[1];
            v.z = bt * head[2];
            v.w = bt * head[3];
            *reinterpret_cast<float4*>(orow + j * 256 + lane * 4) = v;
        }
    }
}

extern "C" void kernel_launch(void* const* d_in, const int* in_sizes, int n_in,
                              void* d_out, int out_size, void* d_ws, size_t ws_size,
                              hipStream_t stream) {
    const float* x   = (const float*)d_in[0];
    const float* sw  = (const float*)d_in[1];
    const float* thr = (const float*)d_in[2];
    const float* lt  = (const float*)d_in[3];
    float* out = (float*)d_out;

    const int batch = in_sizes[0] / IDIM;                 // 16384
    const int waves = (batch + ROWS_PER_WAVE - 1) / ROWS_PER_WAVE;  // 4096
    const int blocks = (waves + 3) / 4;                   // 1024 (4 waves/block)

    osdt_kernel<<<blocks, 256, 0, stream>>>(x, sw, thr, lt, out, batch);
}

// Round 4
// 20.609 us; speedup vs baseline: 1.2570x; 1.2570x over previous
//
#include <hip/hip_runtime.h>
#include <math.h>

// OSDT: soft decision tree leaf probabilities.
// x:[B,512] f32, w:[10,512] f32, thr:[10], lt:[10]  ->  out:[B,1024] f32
// Memory-bound: 32 MiB read + 64 MiB write => roofline ~16 us at 6.3 TB/s.
//
// Decomposition: one 16-lane subgroup per row (4 rows/wave, single pass).
//  - lane holds 32 x-elements (8 float4, issued up-front for MLP)
//  - weights streamed from LDS (no 80-VGPR hoist -> 16 waves/CU)
//  - reduction = 4 butterfly steps (masks 1/2/4/8, DPP-friendly) per depth
//  - sigmoids computed once per subgroup (4x less redundant VALU)

#define IDIM   512
#define DEPTH  10
#define NLEAF  1024

__global__ __launch_bounds__(256, 4) void osdt_kernel(
    const float* __restrict__ x,
    const float* __restrict__ sw,
    const float* __restrict__ thr,
    const float* __restrict__ lt,
    float* __restrict__ out,
    int batch)
{
    __shared__ float4 s_w4[DEPTH * IDIM / 4];   // 1280 float4 = 20 KiB

    const int lane = threadIdx.x & 63;
    const int wave = threadIdx.x >> 6;
    const int g    = lane & 15;                 // lane within subgroup
    const int sg   = lane >> 4;                 // subgroup 0..3
    const int row  = blockIdx.x * 16 + wave * 4 + sg;
    const int crow = row < batch ? row : batch - 1;   // clamped for loads

    // Issue all 8 x-loads first (32 elems/lane); they fly while we stage LDS.
    // Subgroup reads 256B-contiguous segments: byte off = g*16 + c*256.
    float4 xv[8];
    {
        const float4* xr = reinterpret_cast<const float4*>(x + (size_t)crow * IDIM);
        #pragma unroll
        for (int c = 0; c < 8; ++c) xv[c] = xr[c * 16 + g];
    }

    // Stage the 20 KiB weight matrix into LDS (overlaps with x loads).
    {
        const float4* src = reinterpret_cast<const float4*>(sw);
        #pragma unroll
        for (int i = 0; i < 5; ++i)
            s_w4[threadIdx.x + i * 256] = src[threadIdx.x + i * 256];
    }
    float thrv[DEPTH], sclv[DEPTH];
    #pragma unroll
    for (int d = 0; d < DEPTH; ++d) {
        thrv[d] = thr[d];
        sclv[d] = __expf(-lt[d]);
    }
    __syncthreads();

    // Per-depth partial dots: weights streamed from LDS (subgroups 0..3 read
    // identical addresses -> LDS broadcast; within a subgroup 16 lanes x 16B
    // = 2-way bank aliasing = free).
    float part[DEPTH];
    #pragma unroll
    for (int d = 0; d < DEPTH; ++d) {
        float a0 = 0.0f, a1 = 0.0f;
        #pragma unroll
        for (int c = 0; c < 8; c += 2) {
            const float4 w0 = s_w4[d * 128 + c * 16 + g];
            const float4 w1 = s_w4[d * 128 + (c + 1) * 16 + g];
            a0 += xv[c].x * w0.x + xv[c].y * w0.y +
                  xv[c].z * w0.z + xv[c].w * w0.w;
            a1 += xv[c + 1].x * w1.x + xv[c + 1].y * w1.y +
                  xv[c + 1].z * w1.z + xv[c + 1].w * w1.w;
        }
        part[d] = a0 + a1;
    }

    // Butterfly reduce within the 16-lane subgroup (masks 1,2,4,8 stay
    // inside the subgroup); result broadcast to all 16 lanes.
    #pragma unroll
    for (int d = 0; d < DEPTH; ++d) {
        #pragma unroll
        for (int m = 1; m < 16; m <<= 1)
            part[d] += __shfl_xor(part[d], m, 64);
    }

    // Sigmoids. Clamp |z|<=30: |dot| can reach ~100 and expf overflows to
    // inf (inf*0 = NaN). sigmoid(30)=1-9e-14 << 2e-2 tolerance.
    float lv[DEPTH], rv[DEPTH];
    #pragma unroll
    for (int d = 0; d < DEPTH; ++d) {
        float z = (part[d] - thrv[d]) * sclv[d];
        z = fminf(fmaxf(z, -30.0f), 30.0f);
        const float e  = __expf(-z);
        const float rr = 1.0f / (1.0f + e);   // sigmoid(z)
        rv[d] = rr;
        lv[d] = e * rr;                       // sigmoid(-z)
    }

    // Leaf l = c*64 + g*4 + k:
    //   bits 0,1 = k       -> depths 0,1 (head)
    //   bits 2..5 = g      -> depths 2..5 (base, lane-specific)
    //   bits 6..9 = c      -> depths 6..9 (t67 x t89)
    float base = ((g & 1) ? rv[2] : lv[2]) * ((g & 2) ? rv[3] : lv[3]) *
                 ((g & 4) ? rv[4] : lv[4]) * ((g & 8) ? rv[5] : lv[5]);
    float hb[4];
    hb[0] = lv[0] * lv[1] * base;  hb[1] = rv[0] * lv[1] * base;
    hb[2] = lv[0] * rv[1] * base;  hb[3] = rv[0] * rv[1] * base;
    float t67[4], t89[4];
    t67[0] = lv[6] * lv[7];  t67[1] = rv[6] * lv[7];
    t67[2] = lv[6] * rv[7];  t67[3] = rv[6] * rv[7];
    t89[0] = lv[8] * lv[9];  t89[1] = rv[8] * lv[9];
    t89[2] = lv[8] * rv[9];  t89[3] = rv[8] * rv[9];

    if (row >= batch) return;

    // 16 float4 stores; subgroup writes 256B-contiguous segments.
    float* orow = out + (size_t)row * NLEAF;
    #pragma unroll
    for (int c = 0; c < 16; ++c) {
        const float t = t67[c & 3] * t89[c >> 2];   // c compile-time (unrolled)
        float4 v;
        v.x = hb[0] * t;
        v.y = hb[1] * t;
        v.z = hb[2] * t;
        v.w = hb[3] * t;
        *reinterpret_cast<float4*>(orow + c * 64 + g * 4) = v;
    }
}

extern "C" void kernel_launch(void* const* d_in, const int* in_sizes, int n_in,
                              void* d_out, int out_size, void* d_ws, size_t ws_size,
                              hipStream_t stream) {
    const float* x   = (const float*)d_in[0];
    const float* sw  = (const float*)d_in[1];
    const float* thr = (const float*)d_in[2];
    const float* lt  = (const float*)d_in[3];
    float* out = (float*)d_out;

    const int batch  = in_sizes[0] / IDIM;        // 16384
    const int blocks = (batch + 15) / 16;         // 1024 (16 rows/block)

    osdt_kernel<<<blocks, 256, 0, stream>>>(x, sw, thr, lt, out, batch);
}